// Round 4
// baseline (840.874 us; speedup 1.0000x reference)
//
#include <hip/hip_runtime.h>

#define NB 256   // batch
#define NT 512   // time steps
#define ND 128   // input dim
#define NU 128   // hidden dim
#define NC 64    // classes
#define ROWS 16          // batch rows per chain/block
#define NCHAIN (NB / ROWS)
#define YP 136           // LDS row pitch (halfs): 272 B, 16B-aligned, bank-skewed
#define RING 8           // th ring slots
#define LAG 4            // th produced LAG steps ahead

typedef _Float16 half8 __attribute__((ext_vector_type(8)));
typedef _Float16 half4 __attribute__((ext_vector_type(4)));
typedef float f32x4 __attribute__((ext_vector_type(4)));

#define MFMA(a, b, c) __builtin_amdgcn_mfma_f32_16x16x32_f16((a), (b), (c), 0, 0, 0)

// tanh from pre-scaled s=2x: tanh = 1 - 2/(e^s+1); exact limits at +-inf.
__device__ __forceinline__ float tanh_s(float s) {
  float e = __expf(s);
  return fmaf(-2.0f, __builtin_amdgcn_rcpf(e + 1.0f), 1.0f);
}

// LDS-only barrier (no vmem drain).
__device__ __forceinline__ void wg_barrier() {
  asm volatile("s_waitcnt lgkmcnt(0)\n\ts_barrier" ::: "memory");
}

// A-operand frag of W^T: lane (v,q) holds W^T[colW+v][k0+j] = W[(k0+j)*ldw + colW+v]
__device__ __forceinline__ half8 wfrag(const float* W, int ldw, int k0, int col, float sc) {
  half8 h;
#pragma unroll
  for (int j = 0; j < 8; ++j) h[j] = (_Float16)(W[(k0 + j) * ldw + col] * sc);
  return h;
}

__device__ __forceinline__ half8 cvt8(const float4& a, const float4& b) {
  half8 h;
  h[0]=(_Float16)a.x; h[1]=(_Float16)a.y; h[2]=(_Float16)a.z; h[3]=(_Float16)a.w;
  h[4]=(_Float16)b.x; h[5]=(_Float16)b.y; h[6]=(_Float16)b.z; h[7]=(_Float16)b.w;
  return h;
}

// Block: 512 threads = 8 waves, one 16-row chain.
//  waves 0..3 (consumer): R hidden-tiles {2w,2w+1} + classifier tile w.
//  waves 4..7 (producer): th = tanh(x@W1+b1) for hidden-tiles {2p,2p+1}, LAG ahead.
// All MFMAs in transposed orientation: D = W^T(A) * y^T(B) -> regs hidden-contiguous.
__global__ __launch_bounds__(512, 1) void rnn_chain(
    const float* __restrict__ x,   // (B,T,D)
    const float* __restrict__ W1,  // (D,U)
    const float* __restrict__ b1v, // (U)
    const float* __restrict__ W2,  // (U,U)
    const float* __restrict__ b2v, // (U)
    const float* __restrict__ Wc,  // (U,C)
    const float* __restrict__ bcv, // (C)
    float* __restrict__ out)       // (B,T,C)
{
  __shared__ _Float16 Y[2][ROWS * YP];     // y[v][h], double-buffered
  __shared__ _Float16 TH[RING][ROWS * YP]; // tanh(h)[v][h] ring

  const int tid = (int)threadIdx.x;
  const int w   = tid >> 6;      // wave 0..7
  const int L   = tid & 63;
  const int v   = L & 15;        // batch row within chain / B-col / A-row index
  const int q   = L >> 4;        // quad
  const int b0  = (int)blockIdx.x * ROWS;

  // zero Y[1] (read as y_{-1} at t=0)
  for (int i = tid; i < (ROWS * YP) / 2; i += 512) ((unsigned*)Y[1])[i] = 0u;

  if (w < 4) {
    // ================= consumer =================
    const int ht0 = 2 * w, ht1 = 2 * w + 1;
    half8 w2f[2][4], wcf[4];
#pragma unroll
    for (int kk = 0; kk < 4; ++kk) {
      const int k0 = 32 * kk + 8 * q;
      w2f[0][kk] = wfrag(W2, NU, k0, 16 * ht0 + v, 2.0f);
      w2f[1][kk] = wfrag(W2, NU, k0, 16 * ht1 + v, 2.0f);
      wcf[kk]    = wfrag(Wc, NC, k0, 16 * w + v, 1.0f);
    }
    // bias vectors in D layout (regs = hidden-contiguous)
    f32x4 b2f0, b2f1, bcf;
    {
      float4 a = *(const float4*)&b2v[16 * ht0 + 4 * q];
      float4 b = *(const float4*)&b2v[16 * ht1 + 4 * q];
      float4 c = *(const float4*)&bcv[16 * w + 4 * q];
      b2f0 = (f32x4){a.x * 2.f, a.y * 2.f, a.z * 2.f, a.w * 2.f};
      b2f1 = (f32x4){b.x * 2.f, b.y * 2.f, b.z * 2.f, b.w * 2.f};
      bcf  = (f32x4){c.x, c.y, c.z, c.w};
    }
    float* outp = out + ((size_t)(b0 + v) * NT) * NC + 16 * w + 4 * q;

    __syncthreads();  // wait for th(0..LAG-1)

#pragma unroll 1
    for (int t = 0; t < NT; ++t) {
      wg_barrier();
      // B-frags of y_{t-1}^T from Y[(t+1)&1]
      const _Float16* yb = &Y[(t + 1) & 1][v * YP + 8 * q];
      half8 yf0 = *(const half8*)(yb + 0);
      half8 yf1 = *(const half8*)(yb + 32);
      half8 yf2 = *(const half8*)(yb + 64);
      half8 yf3 = *(const half8*)(yb + 96);
      // th(t) from ring (hidden-contiguous 4 halfs per tile)
      half4 th0 = *(const half4*)&TH[t & (RING - 1)][v * YP + 16 * ht0 + 4 * q];
      half4 th1 = *(const half4*)&TH[t & (RING - 1)][v * YP + 16 * ht1 + 4 * q];

      f32x4 r0 = b2f0, r1 = b2f1, co = bcf;
      r0 = MFMA(w2f[0][0], yf0, r0);  r1 = MFMA(w2f[1][0], yf0, r1);
      r0 = MFMA(w2f[0][1], yf1, r0);  r1 = MFMA(w2f[1][1], yf1, r1);
      r0 = MFMA(w2f[0][2], yf2, r0);  r1 = MFMA(w2f[1][2], yf2, r1);
      r0 = MFMA(w2f[0][3], yf3, r0);  r1 = MFMA(w2f[1][3], yf3, r1);
      co = MFMA(wcf[0], yf0, co);
      co = MFMA(wcf[1], yf1, co);
      co = MFMA(wcf[2], yf2, co);
      co = MFMA(wcf[3], yf3, co);

      // y_t = th + tanh(r)  -> f16 -> Y[t&1], vectorized b64 per tile
      half4 o0, o1;
#pragma unroll
      for (int r = 0; r < 4; ++r) {
        o0[r] = (_Float16)((float)th0[r] + tanh_s(r0[r]));
        o1[r] = (_Float16)((float)th1[r] + tanh_s(r1[r]));
      }
      *(half4*)&Y[t & 1][v * YP + 16 * ht0 + 4 * q] = o0;
      *(half4*)&Y[t & 1][v * YP + 16 * ht1 + 4 * q] = o1;

      // out[t-1] = y_{t-1} @ Wc + bc  (regs class-contiguous -> dwordx4)
      if (t >= 1) *(float4*)(outp + (size_t)(t - 1) * NC) = { co[0], co[1], co[2], co[3] };
    }

    // epilogue: out[NT-1] from y_{NT-1} in Y[(NT-1)&1]
    wg_barrier();
    {
      const _Float16* yb = &Y[(NT - 1) & 1][v * YP + 8 * q];
      half8 yf0 = *(const half8*)(yb + 0);
      half8 yf1 = *(const half8*)(yb + 32);
      half8 yf2 = *(const half8*)(yb + 64);
      half8 yf3 = *(const half8*)(yb + 96);
      f32x4 co = bcf;
      co = MFMA(wcf[0], yf0, co);
      co = MFMA(wcf[1], yf1, co);
      co = MFMA(wcf[2], yf2, co);
      co = MFMA(wcf[3], yf3, co);
      *(float4*)(outp + (size_t)(NT - 1) * NC) = { co[0], co[1], co[2], co[3] };
    }
  } else {
    // ================= producer =================
    const int p = w - 4;
    const int ht0 = 2 * p, ht1 = 2 * p + 1;
    half8 w1f[2][4];
#pragma unroll
    for (int kk = 0; kk < 4; ++kk) {
      const int k0 = 32 * kk + 8 * q;
      w1f[0][kk] = wfrag(W1, NU, k0, 16 * ht0 + v, 2.0f);
      w1f[1][kk] = wfrag(W1, NU, k0, 16 * ht1 + v, 2.0f);
    }
    f32x4 b1f0, b1f1;
    {
      float4 a = *(const float4*)&b1v[16 * ht0 + 4 * q];
      float4 b = *(const float4*)&b1v[16 * ht1 + 4 * q];
      b1f0 = (f32x4){a.x * 2.f, a.y * 2.f, a.z * 2.f, a.w * 2.f};
      b1f1 = (f32x4){b.x * 2.f, b.y * 2.f, b.z * 2.f, b.w * 2.f};
    }
    const float* xp = x + (size_t)(b0 + v) * NT * ND + 8 * q;

    // prologue: th(0..LAG-1) into ring
#pragma unroll 1
    for (int s = 0; s < LAG; ++s) {
      half8 xf[4];
#pragma unroll
      for (int kk = 0; kk < 4; ++kk) {
        float4 a = *(const float4*)(xp + (size_t)s * ND + 32 * kk);
        float4 b = *(const float4*)(xp + (size_t)s * ND + 32 * kk + 4);
        xf[kk] = cvt8(a, b);
      }
      f32x4 h0 = b1f0, h1 = b1f1;
#pragma unroll
      for (int kk = 0; kk < 4; ++kk) {
        h0 = MFMA(w1f[0][kk], xf[kk], h0);
        h1 = MFMA(w1f[1][kk], xf[kk], h1);
      }
      half4 o0, o1;
#pragma unroll
      for (int r = 0; r < 4; ++r) {
        o0[r] = (_Float16)tanh_s(h0[r]);
        o1[r] = (_Float16)tanh_s(h1[r]);
      }
      *(half4*)&TH[s][v * YP + 16 * ht0 + 4 * q] = o0;
      *(half4*)&TH[s][v * YP + 16 * ht1 + 4 * q] = o1;
    }
    // pipeline regs: x(LAG) in flight
    float4 xra[4], xrb[4];
#pragma unroll
    for (int kk = 0; kk < 4; ++kk) {
      xra[kk] = *(const float4*)(xp + (size_t)LAG * ND + 32 * kk);
      xrb[kk] = *(const float4*)(xp + (size_t)LAG * ND + 32 * kk + 4);
    }
    __syncthreads();

#pragma unroll 1
    for (int t = 0; t < NT; ++t) {
      wg_barrier();
      // produce th(t+LAG) from regs; refill with x(t+LAG+1)
      half8 xf0 = cvt8(xra[0], xrb[0]);
      half8 xf1 = cvt8(xra[1], xrb[1]);
      half8 xf2 = cvt8(xra[2], xrb[2]);
      half8 xf3 = cvt8(xra[3], xrb[3]);
      {
        int sn = t + LAG + 1; sn = sn < NT ? sn : NT - 1;
#pragma unroll
        for (int kk = 0; kk < 4; ++kk) {
          xra[kk] = *(const float4*)(xp + (size_t)sn * ND + 32 * kk);
          xrb[kk] = *(const float4*)(xp + (size_t)sn * ND + 32 * kk + 4);
        }
      }
      f32x4 h0 = b1f0, h1 = b1f1;
      h0 = MFMA(w1f[0][0], xf0, h0);  h1 = MFMA(w1f[1][0], xf0, h1);
      h0 = MFMA(w1f[0][1], xf1, h0);  h1 = MFMA(w1f[1][1], xf1, h1);
      h0 = MFMA(w1f[0][2], xf2, h0);  h1 = MFMA(w1f[1][2], xf2, h1);
      h0 = MFMA(w1f[0][3], xf3, h0);  h1 = MFMA(w1f[1][3], xf3, h1);
      half4 o0, o1;
#pragma unroll
      for (int r = 0; r < 4; ++r) {
        o0[r] = (_Float16)tanh_s(h0[r]);
        o1[r] = (_Float16)tanh_s(h1[r]);
      }
      const int slot = (t + LAG) & (RING - 1);
      *(half4*)&TH[slot][v * YP + 16 * ht0 + 4 * q] = o0;
      *(half4*)&TH[slot][v * YP + 16 * ht1 + 4 * q] = o1;
    }
    wg_barrier();  // match consumer epilogue barrier
  }
}

extern "C" void kernel_launch(void* const* d_in, const int* in_sizes, int n_in,
                              void* d_out, int out_size, void* d_ws, size_t ws_size,
                              hipStream_t stream) {
  (void)in_sizes; (void)n_in; (void)d_ws; (void)ws_size; (void)out_size;
  const float* x   = (const float*)d_in[0];
  const float* W1  = (const float*)d_in[1];
  const float* b1v = (const float*)d_in[2];
  const float* W2  = (const float*)d_in[3];
  const float* b2v = (const float*)d_in[4];
  const float* Wc  = (const float*)d_in[5];
  const float* bcv = (const float*)d_in[6];
  float* out = (float*)d_out;

  hipLaunchKernelGGL(rnn_chain, dim3(NCHAIN), dim3(512), 0, stream,
                     x, W1, b1v, W2, b2v, Wc, bcv, out);
}

// Round 6
// 315.638 us; speedup vs baseline: 2.6640x; 2.6640x over previous
//
#include <hip/hip_runtime.h>

#define NB 256   // batch
#define NT 512   // time steps
#define ND 128   // input dim
#define NU 128   // hidden dim
#define NC 64    // classes
#define NM (NB * NT)   // 131072 flat rows
#define YP 136         // LDS row pitch in halfs (272B, 16B-aligned)

typedef _Float16 half2v __attribute__((ext_vector_type(2)));
typedef _Float16 half4v __attribute__((ext_vector_type(4)));
typedef _Float16 half8v __attribute__((ext_vector_type(8)));
typedef float f32x4 __attribute__((ext_vector_type(4)));
typedef float v2f __attribute__((ext_vector_type(2)));

#define MFMA(a, b, c) __builtin_amdgcn_mfma_f32_16x16x32_f16((a), (b), (c), 0, 0, 0)

// packed f32x2 -> f16x2 (cvt_pkrtz returns __fp16 vec; bit_cast to our type)
__device__ __forceinline__ half2v pk2(float a, float b) {
  return __builtin_bit_cast(half2v, __builtin_amdgcn_cvt_pkrtz(a, b));
}

// tanh from pre-scaled s=2x: tanh(x) = 1 - 2/(e^s+1); exact limits at +-inf.
__device__ __forceinline__ float tanh_s(float s) {
  float e = __expf(s);
  return fmaf(-2.0f, __builtin_amdgcn_rcpf(e + 1.0f), 1.0f);
}

// LDS-only barrier (no vmem drain -> prefetches/stores stay in flight).
__device__ __forceinline__ void wg_barrier() {
  asm volatile("s_waitcnt lgkmcnt(0)\n\ts_barrier" ::: "memory");
}

// ===================== K1: TH = tanh(x @ W1 + b1) -> f16 =====================
// 2048 blocks x 256 thr; wave handles 16 flat rows; transposed MFMA
// (D^T = W1^T * x^T) so each lane's 4 outputs are hidden-contiguous.
__global__ __launch_bounds__(256, 1) void k1_inproj(
    const float* __restrict__ x, const float* __restrict__ W1,
    const float* __restrict__ b1v, _Float16* __restrict__ TH)
{
  __shared__ _Float16 W1T[ND * YP];  // W1^T[n][k], pre-scaled by 2
  const int tid = (int)threadIdx.x;
  for (int i = tid; i < ND * NU; i += 256) {
    int k = i >> 7, n = i & 127;
    W1T[n * YP + k] = (_Float16)(2.0f * W1[i]);
  }
  __syncthreads();

  const int L = tid & 63, wv = tid >> 6;
  const int v = L & 15, q = L >> 4;
  const int m0 = (int)blockIdx.x * 64 + wv * 16;

  // B-frags: x^T for row m0+v (contiguous k), f32 -> f16 via packed cvt
  const float* xr = x + (size_t)(m0 + v) * ND + 8 * q;
  half8v xf[4];
#pragma unroll
  for (int kk = 0; kk < 4; ++kk) {
    float4 a = *(const float4*)(xr + 32 * kk);
    float4 b = *(const float4*)(xr + 32 * kk + 4);
    half2v p0 = pk2(a.x, a.y), p1 = pk2(a.z, a.w);
    half2v p2 = pk2(b.x, b.y), p3 = pk2(b.z, b.w);
    xf[kk] = (half8v){p0[0], p0[1], p1[0], p1[1], p2[0], p2[1], p3[0], p3[1]};
  }

#pragma unroll
  for (int ht = 0; ht < 8; ++ht) {
    f32x4 acc;
    {
      float4 bb = *(const float4*)&b1v[16 * ht + 4 * q];
      acc = (f32x4){2.f * bb.x, 2.f * bb.y, 2.f * bb.z, 2.f * bb.w};
    }
#pragma unroll
    for (int kk = 0; kk < 4; ++kk) {
      half8v wa = *(const half8v*)&W1T[(16 * ht + v) * YP + 32 * kk + 8 * q];
      acc = MFMA(wa, xf[kk], acc);
    }
    half2v zlo = pk2(tanh_s(acc[0]), tanh_s(acc[1]));
    half2v zhi = pk2(tanh_s(acc[2]), tanh_s(acc[3]));
    half4v z = {zlo[0], zlo[1], zhi[0], zhi[1]};
    *(half4v*)&TH[(size_t)(m0 + v) * NU + 16 * ht + 4 * q] = z;
  }
}

// ===================== K2: serial recurrence =====================
// 16 blocks x 8 waves; wave w owns hidden tile [16w,16w+16).
// State: racc = r_t (scaled 2x) in C-layout regs. Per step:
//   y_t = th_t + tanh(r_t); LDS exchange; r_{t+1} = y_t@W2*2 + b2*2 (MFMA).
__global__ __launch_bounds__(512, 1) void k2_recur(
    const _Float16* __restrict__ TH, const float* __restrict__ W2,
    const float* __restrict__ b2v, _Float16* __restrict__ Yws)
{
  __shared__ _Float16 Ybuf[2][16 * YP];  // y image [v][h], double-buffered

  const int tid = (int)threadIdx.x;
  const int w = tid >> 6;  // hidden tile 0..7
  const int L = tid & 63;
  const int v = L & 15, q = L >> 4;
  const int b0 = (int)blockIdx.x * 16;

  // A-frags of W2^T for tile w (scaled 2x); one-time strided loads
  half8v w2f[4];
#pragma unroll
  for (int kk = 0; kk < 4; ++kk) {
    half8v h;
#pragma unroll
    for (int j = 0; j < 8; ++j)
      h[j] = (_Float16)(2.0f * W2[(size_t)(32 * kk + 8 * q + j) * NU + 16 * w + v]);
    w2f[kk] = h;
  }
  f32x4 b2f;
  {
    float4 bb = *(const float4*)&b2v[16 * w + 4 * q];
    b2f = (f32x4){2.f * bb.x, 2.f * bb.y, 2.f * bb.z, 2.f * bb.w};
  }

  const _Float16* thp = TH + (size_t)(b0 + v) * NT * NU + 16 * w + 4 * q;
  _Float16* yp = Yws + (size_t)(b0 + v) * NT * NU + 16 * w + 4 * q;

  // th prefetch ring (4 deep)
  half4v thr0 = *(const half4v*)(thp + 0 * NU);
  half4v thr1 = *(const half4v*)(thp + 1 * NU);
  half4v thr2 = *(const half4v*)(thp + 2 * NU);
  half4v thr3 = *(const half4v*)(thp + 3 * NU);

  f32x4 racc = b2f;  // r_0 = b2 (y_{-1} = 0)
  _Float16* wr = &Ybuf[0][0] + v * YP + 16 * w + 4 * q;
  const _Float16* rd = &Ybuf[0][0] + v * YP + 8 * q;

#define K2STEP(T_, THR_, BUF_)                                                \
  {                                                                           \
    const int t_ = (T_);                                                      \
    half2v zlo = pk2(tanh_s(racc[0]), tanh_s(racc[1]));                       \
    half2v zhi = pk2(tanh_s(racc[2]), tanh_s(racc[3]));                       \
    half2v tlo = __builtin_shufflevector(THR_, THR_, 0, 1);                   \
    half2v thi = __builtin_shufflevector(THR_, THR_, 2, 3);                   \
    half2v ylo = zlo + tlo;                                                   \
    half2v yhi = zhi + thi;                                                   \
    half4v y4 = {ylo[0], ylo[1], yhi[0], yhi[1]};                             \
    *(half4v*)(wr + (BUF_) * (16 * YP)) = y4;                                 \
    *(half4v*)(yp + (size_t)t_ * NU) = y4; /* fire-and-forget to ws */        \
    {                                                                         \
      int tn = t_ + 4; tn = tn < NT ? tn : NT - 1;                            \
      THR_ = *(const half4v*)(thp + (size_t)tn * NU);                         \
    }                                                                         \
    wg_barrier();                                                             \
    half8v yf0 = *(const half8v*)(rd + (BUF_) * (16 * YP) + 0);               \
    half8v yf1 = *(const half8v*)(rd + (BUF_) * (16 * YP) + 32);              \
    half8v yf2 = *(const half8v*)(rd + (BUF_) * (16 * YP) + 64);              \
    half8v yf3 = *(const half8v*)(rd + (BUF_) * (16 * YP) + 96);              \
    racc = b2f;                                                               \
    racc = MFMA(w2f[0], yf0, racc);                                           \
    racc = MFMA(w2f[1], yf1, racc);                                           \
    racc = MFMA(w2f[2], yf2, racc);                                           \
    racc = MFMA(w2f[3], yf3, racc);                                           \
  }

#pragma unroll 1
  for (int t = 0; t < NT; t += 4) {
    K2STEP(t + 0, thr0, 0)
    K2STEP(t + 1, thr1, 1)
    K2STEP(t + 2, thr2, 0)
    K2STEP(t + 3, thr3, 1)
  }
}

// ===================== K3: out = Y @ Wc + bc =====================
__global__ __launch_bounds__(256, 1) void k3_head(
    const _Float16* __restrict__ Y, const float* __restrict__ Wc,
    const float* __restrict__ bcv, float* __restrict__ out)
{
  __shared__ _Float16 WcT[NC * YP];  // Wc^T[c][k]
  const int tid = (int)threadIdx.x;
  for (int i = tid; i < NU * NC; i += 256) {
    int k = i >> 6, c = i & 63;
    WcT[c * YP + k] = (_Float16)Wc[i];
  }
  __syncthreads();

  const int L = tid & 63, wv = tid >> 6;
  const int v = L & 15, q = L >> 4;
  const int m0 = (int)blockIdx.x * 64 + wv * 16;

  const _Float16* yr = Y + (size_t)(m0 + v) * NU + 8 * q;
  half8v yf[4];
#pragma unroll
  for (int kk = 0; kk < 4; ++kk) yf[kk] = *(const half8v*)(yr + 32 * kk);

  float* op = out + (size_t)(m0 + v) * NC + 4 * q;
#pragma unroll
  for (int ct = 0; ct < 4; ++ct) {
    f32x4 acc;
    {
      float4 bb = *(const float4*)&bcv[16 * ct + 4 * q];
      acc = (f32x4){bb.x, bb.y, bb.z, bb.w};
    }
#pragma unroll
    for (int kk = 0; kk < 4; ++kk) {
      half8v wa = *(const half8v*)&WcT[(16 * ct + v) * YP + 32 * kk + 8 * q];
      acc = MFMA(wa, yf[kk], acc);
    }
    *(float4*)(op + 16 * ct) = (float4){acc[0], acc[1], acc[2], acc[3]};
  }
}

// ===================== fallback (round-2 kernel, no workspace) =====================
__device__ __forceinline__ float fast_tanh(float x) {
  float e = __expf(2.0f * x);
  return 1.0f - 2.0f / (e + 1.0f);
}
__device__ __forceinline__ float bcast(float val, int i) {
  return __builtin_bit_cast(float, __builtin_amdgcn_readlane(__builtin_bit_cast(int, val), i));
}

__global__ __launch_bounds__(256, 1) void rnn_fallback(
    const float* __restrict__ x, const float* __restrict__ W1,
    const float* __restrict__ b1v, const float* __restrict__ W2,
    const float* __restrict__ b2v, const float* __restrict__ Wc,
    const float* __restrict__ bcv, float* __restrict__ out)
{
  __shared__ float xring[16][ND];
  __shared__ float pH[2][4][NU];
  __shared__ float pR[2][4][NU];
  __shared__ float pC[2][4][NC];

  const int tid  = (int)threadIdx.x;
  const int lane = tid & 63;
  const int kg   = tid >> 6;
  const int b    = (int)blockIdx.x;
  const float4* xr4 = (const float4*)(x + (size_t)b * NT * ND);

  v2f w1f[32], w2f[32];
  float wcf[32];
#pragma unroll
  for (int i = 0; i < 32; ++i) {
    int k = kg * 32 + i;
    w1f[i] = (v2f){W1[k * NU + lane], W1[k * NU + lane + 64]};
    w2f[i] = (v2f){W2[k * NU + lane], W2[k * NU + lane + 64]};
    wcf[i] = Wc[k * NC + lane];
  }
  const float biasc = bcv[lane];
  float bias1 = 0.f, bias2 = 0.f;
  if (lane < 32) { bias1 = b1v[kg * 32 + lane]; bias2 = b2v[kg * 32 + lane]; }

  float4 stg = make_float4(0.f, 0.f, 0.f, 0.f);
  if (lane < 32) {
    float4 a0 = xr4[(kg + 0) * 32 + lane];
    float4 a1 = xr4[(kg + 4) * 32 + lane];
    ((float4*)xring[kg + 0])[lane] = a0;
    ((float4*)xring[kg + 4])[lane] = a1;
    stg = xr4[(kg + 8) * 32 + lane];
  }
  float yseg = 0.f;
  wg_barrier();

  for (int t = 0; t < NT; ++t) {
    const int pb = t & 1;
    v2f accH0 = {0.f, 0.f}, accH1 = {0.f, 0.f};
    const float4* xb = (const float4*)&xring[t & 15][kg * 32];
#pragma unroll
    for (int i = 0; i < 4; ++i) {
      float4 xa = xb[2 * i];
      float4 xc = xb[2 * i + 1];
      accH0 = w1f[8*i+0] * (v2f){xa.x, xa.x} + accH0;
      accH1 = w1f[8*i+1] * (v2f){xa.y, xa.y} + accH1;
      accH0 = w1f[8*i+2] * (v2f){xa.z, xa.z} + accH0;
      accH1 = w1f[8*i+3] * (v2f){xa.w, xa.w} + accH1;
      accH0 = w1f[8*i+4] * (v2f){xc.x, xc.x} + accH0;
      accH1 = w1f[8*i+5] * (v2f){xc.y, xc.y} + accH1;
      accH0 = w1f[8*i+6] * (v2f){xc.z, xc.z} + accH0;
      accH1 = w1f[8*i+7] * (v2f){xc.w, xc.w} + accH1;
    }
    v2f accH = accH0 + accH1;
    v2f accR0 = {0.f, 0.f}, accR1 = {0.f, 0.f};
    float accC0 = 0.f, accC1 = 0.f;
#pragma unroll
    for (int i = 0; i < 16; ++i) {
      float s0 = bcast(yseg, 2 * i);
      float s1 = bcast(yseg, 2 * i + 1);
      accR0 = w2f[2*i+0] * (v2f){s0, s0} + accR0;
      accR1 = w2f[2*i+1] * (v2f){s1, s1} + accR1;
      accC0 = fmaf(s0, wcf[2*i+0], accC0);
      accC1 = fmaf(s1, wcf[2*i+1], accC1);
    }
    v2f accR = accR0 + accR1;
    float accC = accC0 + accC1;

    pH[pb][kg][lane]      = accH.x;
    pH[pb][kg][lane + 64] = accH.y;
    pR[pb][kg][lane]      = accR.x;
    pR[pb][kg][lane + 64] = accR.y;
    pC[pb][kg][lane]      = accC;

    if (kg == (t & 3)) {
      if (lane < 32) {
        ((float4*)xring[(t + 8) & 15])[lane] = stg;
        int r = t + 12; r = (r < NT) ? r : (NT - 1);
        stg = xr4[r * 32 + lane];
      }
    }
    wg_barrier();
    if (lane < 32) {
      const int j = kg * 32 + lane;
      float hs = bias1, rs = bias2;
#pragma unroll
      for (int g = 0; g < 4; ++g) { hs += pH[pb][g][j]; rs += pR[pb][g][j]; }
      yseg = fast_tanh(hs) + fast_tanh(rs);
    }
    if (kg == ((t + 2) & 3) && t >= 1) {
      float cs = biasc;
#pragma unroll
      for (int g = 0; g < 4; ++g) cs += pC[pb][g][lane];
      out[((size_t)b * NT + (t - 1)) * NC + lane] = cs;
    }
  }
  float accC0 = 0.f, accC1 = 0.f;
#pragma unroll
  for (int i = 0; i < 16; ++i) {
    float s0 = bcast(yseg, 2 * i);
    float s1 = bcast(yseg, 2 * i + 1);
    accC0 = fmaf(s0, wcf[2*i+0], accC0);
    accC1 = fmaf(s1, wcf[2*i+1], accC1);
  }
  pC[0][kg][lane] = accC0 + accC1;
  wg_barrier();
  if (kg == 0) {
    float cs = biasc;
#pragma unroll
    for (int g = 0; g < 4; ++g) cs += pC[0][g][lane];
    out[((size_t)b * NT + (NT - 1)) * NC + lane] = cs;
  }
}

extern "C" void kernel_launch(void* const* d_in, const int* in_sizes, int n_in,
                              void* d_out, int out_size, void* d_ws, size_t ws_size,
                              hipStream_t stream) {
  (void)in_sizes; (void)n_in; (void)out_size;
  const float* x   = (const float*)d_in[0];
  const float* W1  = (const float*)d_in[1];
  const float* b1v = (const float*)d_in[2];
  const float* W2  = (const float*)d_in[3];
  const float* b2v = (const float*)d_in[4];
  const float* Wc  = (const float*)d_in[5];
  const float* bcv = (const float*)d_in[6];
  float* out = (float*)d_out;

  const size_t need = (size_t)NM * NU * 2 * 2;  // TH + Y, f16 each = 64 MiB
  if (ws_size >= need) {
    _Float16* TH = (_Float16*)d_ws;
    _Float16* Yw = TH + (size_t)NM * NU;
    hipLaunchKernelGGL(k1_inproj, dim3(NM / 64), dim3(256), 0, stream, x, W1, b1v, TH);
    hipLaunchKernelGGL(k2_recur, dim3(NB / 16), dim3(512), 0, stream, TH, W2, b2v, Yw);
    hipLaunchKernelGGL(k3_head, dim3(NM / 64), dim3(256), 0, stream, Yw, Wc, bcv, out);
  } else {
    hipLaunchKernelGGL(rnn_fallback, dim3(NB), dim3(256), 0, stream,
                       x, W1, b1v, W2, b2v, Wc, bcv, out);
  }
}